// Round 12
// baseline (1209.803 us; speedup 1.0000x reference)
//
#include <hip/hip_runtime.h>

#define D   128
#define OD  384   // 3*D output row stride
#define NK  25    // KS^2 kernels

typedef __attribute__((ext_vector_type(8))) short bf16x8;
typedef __attribute__((ext_vector_type(4))) float f32x4;

struct __align__(16) ERec {   // edge record, sorted by dst
  int src;
  int bket;          // dst*25 + w00
  unsigned int b01;  // f16 pair: (1-f0)(1-f1) | f0(1-f1)
  unsigned int b23;  // f16 pair: (1-f0)f1 | f0*f1
};

__device__ inline unsigned short f2bf(float f) {
  unsigned int u = __float_as_uint(f);
  u += 0x7fffu + ((u >> 16) & 1u);
  return (unsigned short)(u >> 16);
}
__device__ inline unsigned short f2h(float f) {
  return __builtin_bit_cast(unsigned short, (_Float16)f);
}
__device__ inline float h2f(unsigned int bits16) {
  return (float)__builtin_bit_cast(_Float16, (unsigned short)(bits16 & 0xffffu));
}

// ---------------- counting: deg[dst] and cnt25[(dst,k)] ----------------------

__global__ __launch_bounds__(256) void count_kernel(const int* __restrict__ dstA,
    const float* __restrict__ attr, int E, int* __restrict__ deg,
    int* __restrict__ cnt25) {
  int e = blockIdx.x * 256 + threadIdx.x;
  if (e >= E) return;
  int d = dstA[e];
  atomicAdd(&deg[d], 1);
  float v0 = attr[2 * e] * 4.0f;
  float v1 = attr[2 * e + 1] * 4.0f;
  int i0 = min(3, max(0, (int)v0));
  int i1 = min(3, max(0, (int)v1));
  int b = d * NK + i0 + 5 * i1;
  atomicAdd(&cnt25[b], 1);
  atomicAdd(&cnt25[b + 1], 1);
  atomicAdd(&cnt25[b + 5], 1);
  atomicAdd(&cnt25[b + 6], 1);
}

// ---------------- parallel exclusive scan over cnt[M] -> base[M+1] -----------

__global__ __launch_bounds__(1024) void scan_a_kernel(const int* __restrict__ cnt, int M,
    int* __restrict__ base, int* __restrict__ bsum) {
  __shared__ int tmp[1024];
  int tid = threadIdx.x;
  int e = blockIdx.x * 1024 + tid;
  int v = (e < M) ? cnt[e] : 0;
  tmp[tid] = v;
  __syncthreads();
#pragma unroll
  for (int off = 1; off < 1024; off <<= 1) {
    int t = (tid >= off) ? tmp[tid - off] : 0;
    __syncthreads();
    tmp[tid] += t;
    __syncthreads();
  }
  if (e <= M) base[e] = tmp[tid] - v;  // exclusive
  if (tid == 1023) bsum[blockIdx.x] = tmp[1023];
}

__global__ __launch_bounds__(256) void scan_b_kernel(int* __restrict__ bsum, int nblk) {
  __shared__ int tmp[256];
  __shared__ int carry;
  int tid = threadIdx.x;
  if (tid == 0) carry = 0;
  __syncthreads();
  for (int s = 0; s < nblk; s += 256) {
    int i = s + tid;
    int v = (i < nblk) ? bsum[i] : 0;
    tmp[tid] = v;
    __syncthreads();
#pragma unroll
    for (int off = 1; off < 256; off <<= 1) {
      int t = (tid >= off) ? tmp[tid - off] : 0;
      __syncthreads();
      tmp[tid] += t;
      __syncthreads();
    }
    if (i < nblk) bsum[i] = carry + tmp[tid] - v;
    __syncthreads();
    if (tid == 255) carry += tmp[255];
    __syncthreads();
  }
}

__global__ __launch_bounds__(256) void scan_c_kernel(int* __restrict__ base,
    int* __restrict__ cursor, const int* __restrict__ bsum, int M) {
  int e = blockIdx.x * 256 + threadIdx.x;
  if (e > M) return;
  int v = base[e] + bsum[e >> 10];
  base[e] = v;
  if (e < M) cursor[e] = v;
}

// ---------------- stage A: edge records sorted by dst ------------------------

__global__ __launch_bounds__(256) void fillA_kernel(const int* __restrict__ srcA,
    const int* __restrict__ dstA, const float* __restrict__ attr, int E,
    int* __restrict__ cursorN, ERec* __restrict__ erecs) {
  int e = blockIdx.x * 256 + threadIdx.x;
  if (e >= E) return;
  int d = dstA[e];
  float v0 = attr[2 * e] * 4.0f;
  float v1 = attr[2 * e + 1] * 4.0f;
  int i0 = min(3, max(0, (int)v0));
  int i1 = min(3, max(0, (int)v1));
  float f0 = v0 - (float)i0;
  float f1 = v1 - (float)i1;
  int pos = atomicAdd(&cursorN[d], 1);
  ERec r;
  r.src = srcA[e];
  r.bket = d * NK + i0 + 5 * i1;
  r.b01 = (unsigned int)f2h((1.f - f0) * (1.f - f1)) |
          ((unsigned int)f2h(f0 * (1.f - f1)) << 16);
  r.b23 = (unsigned int)f2h((1.f - f0) * f1) | ((unsigned int)f2h(f0 * f1) << 16);
  erecs[pos] = r;
}

// ---------------- stage B: corner records sorted by (dst,k) ------------------
// reads dst-sorted edges -> stores cluster within each dst's corner region.

__global__ __launch_bounds__(256) void fillB_kernel(const ERec* __restrict__ erecs,
    int E, int* __restrict__ cursor25, uint2* __restrict__ crecs) {
  int e = blockIdx.x * 256 + threadIdx.x;
  if (e >= E) return;
  ERec r = erecs[e];
  unsigned int su = (unsigned int)r.src;
  int p;
  p = atomicAdd(&cursor25[r.bket], 1);
  crecs[p] = make_uint2(su, __float_as_uint(h2f(r.b01)));
  p = atomicAdd(&cursor25[r.bket + 1], 1);
  crecs[p] = make_uint2(su, __float_as_uint(h2f(r.b01 >> 16)));
  p = atomicAdd(&cursor25[r.bket + 5], 1);
  crecs[p] = make_uint2(su, __float_as_uint(h2f(r.b23)));
  p = atomicAdd(&cursor25[r.bket + 6], 1);
  crecs[p] = make_uint2(su, __float_as_uint(h2f(r.b23 >> 16)));
}

// WT[n][kk] = bf16(W[kk/128][kk%128][n]); gridDim.y selects layer
__global__ __launch_bounds__(256) void wt_kernel(const float* __restrict__ W0,
    const float* __restrict__ W1, unsigned short* __restrict__ WT0,
    unsigned short* __restrict__ WT1) {
  int idx = blockIdx.x * 256 + threadIdx.x;  // over 128*3200
  if (idx >= 128 * NK * D) return;
  const float* W = blockIdx.y ? W1 : W0;
  unsigned short* WT = blockIdx.y ? WT1 : WT0;
  int n = idx / (NK * D);
  int kk = idx - n * (NK * D);
  WT[idx] = f2bf(W[(size_t)kk * D + n]);
}

// ---------------- fused gather+MFMA: Y[128-dst tile] = sum_k G_k @ W[k] ------
// 512 thr = 8 waves; 13 chunks of KC=2. Gather: wave owns 16 dsts, REGISTER
// accumulators (corner-sorted recs), writes bf16 G-tile to swizzled LDS.
// MFMA: A from LDS, B 16B/lane from L2-resident WT, acc in VGPRs across all
// chunks. G never touches global memory; Y written once.

__global__ __launch_bounds__(512, 4) void fused_kernel(
    const int* __restrict__ base25, const uint2* __restrict__ crecs,
    const unsigned short* __restrict__ Xb, const unsigned short* __restrict__ WT,
    float* __restrict__ Y, int N) {
  __shared__ unsigned int Gl[16384];  // 64KB: 128 rows x 512B (2k x 128ch bf16)
  const int tid = threadIdx.x;
  const int w = tid >> 6, l = tid & 63;
  const int blk = blockIdx.x;
  const int mgrp = w >> 2, ngrp = w & 3;  // 2 M-groups x 4 N-groups

  f32x4 acc[4][2];
#pragma unroll
  for (int mr = 0; mr < 4; ++mr)
#pragma unroll
    for (int c = 0; c < 2; ++c) acc[mr][c] = (f32x4){0.f, 0.f, 0.f, 0.f};

  for (int chunk = 0; chunk < 13; ++chunk) {
    const int k0 = chunk * 2;
    // ---- gather phase: each wave fills its 16 LDS G rows ----
    for (int i = 0; i < 16; ++i) {
      int m = w * 16 + i;
      int dst = blk * 128 + m;
      float2 a0 = make_float2(0.f, 0.f), a1 = make_float2(0.f, 0.f);
      if (dst < N) {
        const int* bp = base25 + dst * NK + k0;
        int s0 = __builtin_amdgcn_readfirstlane(bp[0]);
        int e1 = __builtin_amdgcn_readfirstlane(bp[1]);
        int e2 = (k0 + 1 < NK) ? __builtin_amdgcn_readfirstlane(bp[2]) : e1;
        for (int j = s0; j < e2; j += 4) {
          uint2 r[4];
          unsigned int xp[4];
#pragma unroll
          for (int u = 0; u < 4; ++u) {
            int idx = (j + u < e2) ? (j + u) : (e2 - 1);
            r[u] = crecs[idx];
          }
#pragma unroll
          for (int u = 0; u < 4; ++u)
            xp[u] = *(const unsigned int*)(Xb + (size_t)r[u].x * D + l * 2);
#pragma unroll
          for (int u = 0; u < 4; ++u) {
            bool valid = (j + u) < e2;
            bool lo = (j + u) < e1;
            float b = valid ? __uint_as_float(r[u].y) : 0.f;
            float b0 = lo ? b : 0.f;
            float b1 = lo ? 0.f : b;
            float x0 = __uint_as_float(xp[u] << 16);
            float x1 = __uint_as_float(xp[u] & 0xffff0000u);
            a0.x = fmaf(b0, x0, a0.x); a0.y = fmaf(b0, x1, a0.y);
            a1.x = fmaf(b1, x0, a1.x); a1.y = fmaf(b1, x1, a1.y);
          }
        }
      }
      unsigned int p0 = (unsigned int)f2bf(a0.x) | ((unsigned int)f2bf(a0.y) << 16);
      unsigned int p1 = (unsigned int)f2bf(a1.x) | ((unsigned int)f2bf(a1.y) << 16);
      int byte0 = (m * 512 + l * 4) ^ ((m & 7) << 4);
      Gl[byte0 >> 2] = p0;
      Gl[(byte0 + 256) >> 2] = p1;
    }
    __syncthreads();
    // ---- MFMA phase: K = KC*128 (=256; 128 for the tail chunk) ----
    const int ksmax = (k0 + 2 <= NK) ? 8 : 4;
    for (int ks = 0; ks < ksmax; ++ks) {
      bf16x8 av[4], bv[2];
#pragma unroll
      for (int mr = 0; mr < 4; ++mr) {
        int r = mgrp * 64 + mr * 16 + (l & 15);
        int byte = (r * 512 + ks * 64 + (l >> 4) * 16) ^ ((r & 7) << 4);
        av[mr] = *(const bf16x8*)((const char*)Gl + byte);
      }
#pragma unroll
      for (int c = 0; c < 2; ++c) {
        int n = ngrp * 32 + c * 16 + (l & 15);
        bv[c] = *(const bf16x8*)(WT + (size_t)n * (NK * D) + chunk * 256 + ks * 32 +
                                 (l >> 4) * 8);
      }
#pragma unroll
      for (int mr = 0; mr < 4; ++mr)
#pragma unroll
        for (int c = 0; c < 2; ++c)
          acc[mr][c] =
              __builtin_amdgcn_mfma_f32_16x16x32_bf16(av[mr], bv[c], acc[mr][c], 0, 0, 0);
    }
    __syncthreads();
  }

#pragma unroll
  for (int mr = 0; mr < 4; ++mr)
#pragma unroll
    for (int c = 0; c < 2; ++c) {
      int col = ngrp * 32 + c * 16 + (l & 15);
#pragma unroll
      for (int j = 0; j < 4; ++j) {
        int row = blk * 128 + mgrp * 64 + mr * 16 + (l >> 4) * 4 + j;
        if (row < N) Y[(size_t)row * D + col] = acc[mr][c][j];
      }
    }
}

// ---------------- per-row l2norm / finalize ----------------------------------

__global__ __launch_bounds__(256) void l2norm_x_kernel(const float* __restrict__ x,
    float* __restrict__ out, unsigned short* __restrict__ xbf, int N) {
  int g = blockIdx.x * 256 + threadIdx.x;
  int n = g >> 6, lane = g & 63;
  if (n >= N) return;
  float2 v = *(const float2*)(x + (size_t)n * D + lane * 2);
  float ss = v.x * v.x + v.y * v.y;
#pragma unroll
  for (int m = 1; m < 64; m <<= 1) ss += __shfl_xor(ss, m, 64);
  float r = 1.0f / fmaxf(sqrtf(ss), 1e-12f);
  *(float2*)(out + (size_t)n * OD + lane * 2) = make_float2(v.x * r, v.y * r);
  unsigned int pk = (unsigned int)f2bf(v.x) | ((unsigned int)f2bf(v.y) << 16);
  *(unsigned int*)(xbf + (size_t)n * D + lane * 2) = pk;
}

__global__ __launch_bounds__(256) void finalize_kernel(const float* __restrict__ y,
    const int* __restrict__ deg, const float* __restrict__ bias, float* __restrict__ out,
    unsigned short* __restrict__ xnext, int N) {
  int g = blockIdx.x * 256 + threadIdx.x;
  int n = g >> 6, lane = g & 63;
  if (n >= N) return;
  float inv = 1.0f / (float)max(deg[n], 1);
  float2 a = *(const float2*)(y + (size_t)n * D + lane * 2);
  float2 b = *(const float2*)(bias + lane * 2);
  float h0 = a.x * inv + b.x;
  float h1 = a.y * inv + b.y;
  float ss = h0 * h0 + h1 * h1;
#pragma unroll
  for (int m = 1; m < 64; m <<= 1) ss += __shfl_xor(ss, m, 64);
  float r = 1.0f / fmaxf(sqrtf(ss), 1e-12f);
  *(float2*)(out + (size_t)n * OD + lane * 2) = make_float2(h0 * r, h1 * r);
  if (xnext) {
    unsigned int pk = (unsigned int)f2bf(fmaxf(h0, 0.f)) |
                      ((unsigned int)f2bf(fmaxf(h1, 0.f)) << 16);
    *(unsigned int*)(xnext + (size_t)n * D + lane * 2) = pk;
  }
}

// ---------------- launch -----------------------------------------------------

extern "C" void kernel_launch(void* const* d_in, const int* in_sizes, int n_in,
                              void* d_out, int out_size, void* d_ws, size_t ws_size,
                              hipStream_t stream) {
  const float* x    = (const float*)d_in[0];
  const int*   ei   = (const int*)d_in[1];
  const float* attr = (const float*)d_in[2];
  const float* w0   = (const float*)d_in[3];
  const float* b0   = (const float*)d_in[4];
  const float* w1   = (const float*)d_in[5];
  const float* b1   = (const float*)d_in[6];
  float* out = (float*)d_out;

  const int N = in_sizes[0] / D;
  const int E = in_sizes[1] / 2;
  const int* srcA = ei;
  const int* dstA = ei + E;
  const int M25 = N * NK;

  char* p = (char*)d_ws;
  auto carve = [&](size_t bytes) -> char* {
    char* r = p;
    p += (bytes + 255) & ~(size_t)255;
    return r;
  };
  unsigned short* xbf      = (unsigned short*)carve((size_t)N * D * 2);
  unsigned short* xtmp     = (unsigned short*)carve((size_t)N * D * 2);
  float*          ygemm    = (float*)carve((size_t)N * D * 4);
  int*            deg      = (int*)carve((size_t)N * 4);
  int*            baseN    = (int*)carve(((size_t)N + 1) * 4);
  int*            cursorN  = (int*)carve((size_t)N * 4);
  int*            cnt25    = (int*)carve((size_t)M25 * 4);
  int*            base25   = (int*)carve(((size_t)M25 + 1) * 4);
  int*            cursor25 = (int*)carve((size_t)M25 * 4);
  int*            bsum     = (int*)carve(8192);
  ERec*           erecs    = (ERec*)carve((size_t)E * sizeof(ERec));
  uint2*          crecs    = (uint2*)carve((size_t)E * 4 * 8);
  unsigned short* WT0      = (unsigned short*)carve((size_t)128 * NK * D * 2);
  unsigned short* WT1      = (unsigned short*)carve((size_t)128 * NK * D * 2);
  (void)n_in; (void)out_size; (void)ws_size;

  hipMemsetAsync(deg, 0, (size_t)N * 4, stream);
  hipMemsetAsync(cnt25, 0, (size_t)M25 * 4, stream);

  int eb = (E + 255) / 256;
  count_kernel<<<eb, 256, 0, stream>>>(dstA, attr, E, deg, cnt25);
  // scan deg -> baseN/cursorN
  int nblkN = (N + 1 + 1023) / 1024;
  scan_a_kernel<<<nblkN, 1024, 0, stream>>>(deg, N, baseN, bsum);
  scan_b_kernel<<<1, 256, 0, stream>>>(bsum, nblkN);
  scan_c_kernel<<<(N + 1 + 255) / 256, 256, 0, stream>>>(baseN, cursorN, bsum, N);
  // scan cnt25 -> base25/cursor25
  int nblk25 = (M25 + 1 + 1023) / 1024;
  scan_a_kernel<<<nblk25, 1024, 0, stream>>>(cnt25, M25, base25, bsum);
  scan_b_kernel<<<1, 256, 0, stream>>>(bsum, nblk25);
  scan_c_kernel<<<(M25 + 1 + 255) / 256, 256, 0, stream>>>(base25, cursor25, bsum, M25);
  // stage A: edges sorted by dst; stage B: corners sorted by (dst,k)
  fillA_kernel<<<eb, 256, 0, stream>>>(srcA, dstA, attr, E, cursorN, erecs);
  fillB_kernel<<<eb, 256, 0, stream>>>(erecs, E, cursor25, crecs);
  int wtb = (128 * NK * D + 255) / 256;
  wt_kernel<<<dim3(wtb, 2), 256, 0, stream>>>(w0, w1, WT0, WT1);

  int nb = (N * 64 + 255) / 256;
  l2norm_x_kernel<<<nb, 256, 0, stream>>>(x, out, xbf, N);

  int fblk = (N + 127) / 128;  // 391 blocks, 2/CU -> one scheduling round
  const unsigned short* xin = xbf;
  const float* Bv[2] = {b0, b1};
  const unsigned short* WTl[2] = {WT0, WT1};
  for (int layer = 0; layer < 2; ++layer) {
    fused_kernel<<<fblk, 512, 0, stream>>>(base25, crecs, xin, WTl[layer], ygemm, N);
    finalize_kernel<<<nb, 256, 0, stream>>>(ygemm, deg, Bv[layer], out + D * (layer + 1),
                                            layer == 0 ? xtmp : nullptr, N);
    xin = xtmp;
  }
}